// Round 18
// baseline (414.366 us; speedup 1.0000x reference)
//
#include <hip/hip_runtime.h>
#include <hip/hip_bf16.h>
#include <math.h>

#define TM1 16
#define TT 17

typedef __attribute__((ext_vector_type(8))) __bf16 bf16x8;
typedef __attribute__((ext_vector_type(4))) __bf16 bf16x4;
typedef __attribute__((ext_vector_type(4))) float f32x4;

// ---------------- workspace layout (float units) ----------------
#define OFF_BSTATS 0          // 32*2048 (TRANSPOSED: [stat][block])
#define OFF_STATS  65536      // 32
#define OFF_POOLED 65568      // 2048*16
#define OFF_BCOL   98336      // 512*12
#define OFF_SPB    104480     // 512*256 bf16 (final pred scratch)
#define OFF_PWB    170016     // 256*512 bf16
#define OFF_WIHB   235552     // 1536*256 bf16
#define OFF_WHHB   432160     // 1536*512 bf16
#define OFF_HB     825376     // 2 x 512*512 bf16
#define OFF_RP     1087520    // 2 x 16*512*256 bf16 = 2 x 1048576 f-units
// total ~12.7 MB

#define IMG_STRIDE 67
#define SLAB_ROWS 18
#define IMG_CI (SLAB_ROWS * IMG_STRIDE)

__device__ __forceinline__ void stage_slab_bf16(__hip_bfloat16* __restrict__ imgp,
                                                const float* __restrict__ xb, int slab,
                                                int tid) {
  for (int i = tid; i < 2 * SLAB_ROWS * 66; i += 256) {
    const int ci = i / (SLAB_ROWS * 66);
    const int rem = i - ci * (SLAB_ROWS * 66);
    const int lr = rem / 66, c = rem - lr * 66;
    const int gr = slab * 16 - 1 + lr;
    float v = 0.0f;
    if (gr >= 0 && gr < 64 && c >= 1 && c <= 64) v = xb[ci * 4096 + gr * 64 + (c - 1)];
    imgp[ci * IMG_CI + lr * IMG_STRIDE + c] = __float2bfloat16(v);
  }
}

__device__ __forceinline__ void make_k_offsets(int hi, int* off, int* val) {
#pragma unroll
  for (int j = 0; j < 8; ++j) {
    const int k = hi * 8 + j;
    if (k < 18) {
      const int ci = k / 9, r9 = k - ci * 9;
      const int dy = r9 / 3, dx = r9 - dy * 3;
      off[j] = ci * IMG_CI + dy * IMG_STRIDE + dx;
      val[j] = 1;
    } else {
      off[j] = 0;
      val[j] = 0;
    }
  }
}

__device__ __forceinline__ bf16x8 make_conv_bfrag(const float* __restrict__ cw,
                                                  int l15, int hi) {
  __hip_bfloat16 btmp[8];
#pragma unroll
  for (int j = 0; j < 8; ++j) {
    const int k = hi * 8 + j;
    btmp[j] = __float2bfloat16((k < 18) ? cw[l15 * 18 + k] : 0.0f);
  }
  return *(bf16x8*)btmp;
}

__device__ __forceinline__ bf16x8 make_conv_afrag(const __hip_bfloat16* __restrict__ imgp,
                                                  int yloc, int x0, int l15,
                                                  const int* off, const int* val) {
  const int base = yloc * IMG_STRIDE + x0 + l15;
  const __hip_bfloat16 z = __float2bfloat16(0.0f);
  __hip_bfloat16 atmp[8];
#pragma unroll
  for (int j = 0; j < 8; ++j) atmp[j] = val[j] ? imgp[base + off[j]] : z;
  return *(bf16x8*)atmp;
}

// ---------------- Encoder pass A (unchanged) ----------------
__global__ __launch_bounds__(256) void enc_stats_prep(
    const float* __restrict__ x, const float* __restrict__ cw,
    float* __restrict__ bstats,
    const float* __restrict__ wih, const float* __restrict__ whh,
    const float* __restrict__ pw,
    const float* __restrict__ bih, const float* __restrict__ bhh,
    __hip_bfloat16* __restrict__ wihb, __hip_bfloat16* __restrict__ whhb,
    __hip_bfloat16* __restrict__ pwb, float* __restrict__ bcol) {
  {
    const int n1 = 1536 * 256, n2 = 1536 * 512, n3 = 256 * 512, n4 = 512 * 12;
    int i = blockIdx.x * 256 + threadIdx.x;
    int st = gridDim.x * 256;
    for (int j = i; j < n1 + n2 + n3 + n4; j += st) {
      if (j < n1) {
        int r = j >> 8, c = j & 255;
        wihb[j] = __float2bfloat16(wih[r * 258 + c]);
      } else if (j < n1 + n2) {
        int k = j - n1;
        whhb[k] = __float2bfloat16(whh[k]);
      } else if (j < n1 + n2 + n3) {
        int k = j - n1 - n2;
        pwb[k] = __float2bfloat16(pw[k]);
      } else {
        int k = j - n1 - n2 - n3;
        int col = k / 12, e = k - col * 12;
        float v = 0.0f;
        switch (e) {
          case 0: v = bih[col] + bhh[col]; break;
          case 1: v = bih[512 + col] + bhh[512 + col]; break;
          case 2: v = bih[1024 + col]; break;
          case 3: v = bhh[1024 + col]; break;
          case 4: v = wih[col * 258 + 256]; break;
          case 5: v = wih[col * 258 + 257]; break;
          case 6: v = wih[(512 + col) * 258 + 256]; break;
          case 7: v = wih[(512 + col) * 258 + 257]; break;
          case 8: v = wih[(1024 + col) * 258 + 256]; break;
          case 9: v = wih[(1024 + col) * 258 + 257]; break;
          default: v = 0.0f; break;
        }
        bcol[k] = v;
      }
    }
  }

  __shared__ __hip_bfloat16 imgp[2 * IMG_CI];
  __shared__ float redS[4][16], redQ[4][16];
  const int tid = threadIdx.x;
  const int b = blockIdx.x >> 2, slab = blockIdx.x & 3;
  const int wv = tid >> 6, lane = tid & 63;
  const int l15 = lane & 15, hi = lane >> 4;
  stage_slab_bf16(imgp, x + b * 8192, slab, tid);

  int off[8], val[8];
  make_k_offsets(hi, off, val);
  const bf16x8 bfrag = make_conv_bfrag(cw, l15, hi);
  __syncthreads();

  float sacc = 0.0f, qacc = 0.0f;
  const f32x4 zero4 = {0.f, 0.f, 0.f, 0.f};
#pragma unroll
  for (int tp = 0; tp < 8; ++tp) {
    const int tpi = wv * 8 + tp;
    const int y0 = (tpi >> 2) * 2, x0 = (tpi & 3) * 16;
    bf16x8 a0 = make_conv_afrag(imgp, y0, x0, l15, off, val);
    bf16x8 a1 = make_conv_afrag(imgp, y0 + 1, x0, l15, off, val);
    f32x4 c0 = __builtin_amdgcn_mfma_f32_16x16x32_bf16(a0, bfrag, zero4, 0, 0, 0);
    f32x4 c1 = __builtin_amdgcn_mfma_f32_16x16x32_bf16(a1, bfrag, zero4, 0, 0, 0);
#pragma unroll
    for (int i = 0; i < 4; ++i) {
      sacc += c0[i] + c1[i];
      qacc = fmaf(c0[i], c0[i], qacc);
      qacc = fmaf(c1[i], c1[i], qacc);
    }
  }
  sacc += __shfl_down(sacc, 16); sacc += __shfl_down(sacc, 32);
  qacc += __shfl_down(qacc, 16); qacc += __shfl_down(qacc, 32);
  if (lane < 16) { redS[wv][l15] = sacc; redQ[wv][l15] = qacc; }
  __syncthreads();
  if (tid < 16)
    bstats[tid * 2048 + blockIdx.x] =
        redS[0][tid] + redS[1][tid] + redS[2][tid] + redS[3][tid];
  else if (tid < 32) {
    int c = tid - 16;
    bstats[tid * 2048 + blockIdx.x] =
        redQ[0][c] + redQ[1][c] + redQ[2][c] + redQ[3][c];
  }
}

__global__ __launch_bounds__(256) void reduce_stats_k(const float* __restrict__ bstats,
                                                      float* __restrict__ stats) {
  __shared__ float acc[4];
  const int c = blockIdx.x, tid = threadIdx.x;
  const float4 v4 = *(const float4*)(bstats + c * 2048 + tid * 8);
  const float4 w4 = *(const float4*)(bstats + c * 2048 + tid * 8 + 4);
  float v = v4.x + v4.y + v4.z + v4.w + w4.x + w4.y + w4.z + w4.w;
#pragma unroll
  for (int off = 32; off >= 1; off >>= 1) v += __shfl_down(v, off);
  if ((tid & 63) == 0) acc[tid >> 6] = v;
  __syncthreads();
  if (tid == 0) stats[c] = acc[0] + acc[1] + acc[2] + acc[3];
}

// ---------------- Encoder pass B (unchanged) ----------------
__global__ __launch_bounds__(256) void enc_pool(const float* __restrict__ x,
                                                const float* __restrict__ cw,
                                                const float* __restrict__ stats,
                                                const float* __restrict__ gamma,
                                                const float* __restrict__ beta,
                                                float* __restrict__ pooledG) {
  __shared__ __hip_bfloat16 imgp[2 * IMG_CI];
  __shared__ float red[4][16];
  __shared__ float statsL[32];
  const int tid = threadIdx.x;
  const int b = blockIdx.x >> 2, slab = blockIdx.x & 3;
  const int wv = tid >> 6, lane = tid & 63;
  const int l15 = lane & 15, hi = lane >> 4;
  stage_slab_bf16(imgp, x + b * 8192, slab, tid);
  if (tid < 32) statsL[tid] = stats[tid];

  int off[8], val[8];
  make_k_offsets(hi, off, val);
  const bf16x8 bfrag = make_conv_bfrag(cw, l15, hi);
  __syncthreads();

  const float invN = 1.0f / (512.0f * 4096.0f);
  const float m = statsL[l15] * invN;
  const float var = statsL[16 + l15] * invN - m * m;
  const float isd = rsqrtf(var + 1e-5f);
  const float scv = gamma[l15] * isd;
  const float shv = beta[l15] - m * scv;

  float psum = 0.0f;
  const f32x4 zero4 = {0.f, 0.f, 0.f, 0.f};
#pragma unroll
  for (int tp = 0; tp < 8; ++tp) {
    const int tpi = wv * 8 + tp;
    const int y0 = (tpi >> 2) * 2, x0 = (tpi & 3) * 16;
    bf16x8 a0 = make_conv_afrag(imgp, y0, x0, l15, off, val);
    bf16x8 a1 = make_conv_afrag(imgp, y0 + 1, x0, l15, off, val);
    f32x4 c0 = __builtin_amdgcn_mfma_f32_16x16x32_bf16(a0, bfrag, zero4, 0, 0, 0);
    f32x4 c1 = __builtin_amdgcn_mfma_f32_16x16x32_bf16(a1, bfrag, zero4, 0, 0, 0);
#pragma unroll
    for (int p = 0; p < 2; ++p) {
      const float v00 = fmaxf(fmaf(c0[2 * p + 0], scv, shv), 0.0f);
      const float v01 = fmaxf(fmaf(c0[2 * p + 1], scv, shv), 0.0f);
      const float v10 = fmaxf(fmaf(c1[2 * p + 0], scv, shv), 0.0f);
      const float v11 = fmaxf(fmaf(c1[2 * p + 1], scv, shv), 0.0f);
      psum += fmaxf(fmaxf(v00, v01), fmaxf(v10, v11));
    }
  }
  psum += __shfl_down(psum, 16);
  psum += __shfl_down(psum, 32);
  if (lane < 16) red[wv][l15] = psum;
  __syncthreads();
  if (tid < 16)
    pooledG[blockIdx.x * 16 + tid] = red[0][tid] + red[1][tid] + red[2][tid] + red[3][tid];
}

// ---------- Fused step v5: 512 blocks (2/CU) x 384 thr; bf16 rp, no hF LDS ----------
// cg = bid>>5 (16 groups x 32 hidden cols), band = bid&31 (16 rows). bid%8==band%8 -> XCD-local rp.
__global__ __launch_bounds__(384) void gru_v5(
    const __hip_bfloat16* __restrict__ hb_in,
    __hip_bfloat16* __restrict__ hb_out,
    const __hip_bfloat16* __restrict__ rp_in,  // [16][512][256] bf16 partials of s(t)
    __hip_bfloat16* __restrict__ rp_out,
    const __hip_bfloat16* __restrict__ wihb,   // [1536][256]
    const __hip_bfloat16* __restrict__ whhb,   // [1536][512]
    const __hip_bfloat16* __restrict__ pwb,    // [256][512]
    const float* __restrict__ pb,
    const float* __restrict__ bcol,            // [512][12]
    const float* __restrict__ actions,
    const float* __restrict__ pooledG, const float* __restrict__ fcw,
    const float* __restrict__ fcb,
    float* __restrict__ out,
    int t) {
  __shared__ __hip_bfloat16 sL[8 * 64 * 8];    // 8KB s(t) A-frags (frag order)
  __shared__ __hip_bfloat16 hS[64 * 8];        // 1KB h(t+1) local tile (K=32 frag order)
  __shared__ float accL[4][2][256];            // 8KB
  const int tid = threadIdx.x;
  const int w = tid / 64, lane = tid & 63;
  const int l15 = lane & 15, hi = lane >> 4;
  const int cg = blockIdx.x >> 5, band = blockIdx.x & 31;
  const int row0 = band * 16;

  if (t > 0) {
    // s(t) = relu(sum of 16 bf16 partial strips + pb)
    for (int i = tid; i < 1024; i += 384) {
      const int row = i >> 6, c4 = (i & 63) * 4;
      float a[4];
      {
        const float4 pb4 = *(const float4*)(pb + c4);
        a[0] = pb4.x; a[1] = pb4.y; a[2] = pb4.z; a[3] = pb4.w;
      }
#pragma unroll
      for (int s = 0; s < 16; ++s) {
        const bf16x4 p = *(const bf16x4*)(rp_in + ((size_t)(s * 512 + row0 + row)) * 256 + c4);
#pragma unroll
        for (int j = 0; j < 4; ++j) a[j] += (float)p[j];
      }
      float4 ov;
      ov.x = fmaxf(a[0], 0.f); ov.y = fmaxf(a[1], 0.f);
      ov.z = fmaxf(a[2], 0.f); ov.w = fmaxf(a[3], 0.f);
      const float av[4] = {ov.x, ov.y, ov.z, ov.w};
#pragma unroll
      for (int j = 0; j < 4; ++j) {
        const int c = c4 + j;
        sL[((c >> 5) * 64 + row + 16 * ((c & 31) >> 3)) * 8 + (c & 7)] =
            __float2bfloat16(av[j]);
      }
      if (cg == 0) *(float4*)(out + ((size_t)(row0 + row) * TT + t) * 256 + c4) = ov;
    }
  } else {
    float* avgF = &accL[0][0][0];
    if (tid < 256) {
      const int r = tid >> 4, k = tid & 15;
      const int img = row0 + r;
      const float v = pooledG[(img * 4 + 0) * 16 + k] + pooledG[(img * 4 + 1) * 16 + k] +
                      pooledG[(img * 4 + 2) * 16 + k] + pooledG[(img * 4 + 3) * 16 + k];
      avgF[r * 16 + k] = v * (1.0f / 1024.0f);
    }
    __syncthreads();
    for (int i = tid; i < 4096; i += 384) {
      const int r = i >> 8, col = i & 255;
      float v = fcb[col];
#pragma unroll
      for (int k = 0; k < 16; ++k) v = fmaf(avgF[r * 16 + k], fcw[col * 16 + k], v);
      sL[((col >> 5) * 64 + r + 16 * ((col & 31) >> 3)) * 8 + (col & 7)] =
          __float2bfloat16(v);
      if (cg == 0) out[((size_t)(row0 + r) * TT + 0) * 256 + col] = v;
    }
    __syncthreads();  // avgF (accL alias) fully read before gates write accL
  }
  __syncthreads();

  // ---- gates: 6 jobs (g = w>>1, ct2 = w&1), one per wave ----
  {
    const int g = w >> 1, ct2 = w & 1;
    const int jb = cg * 32 + ct2 * 16 + l15;
    f32x4 accS = {0.f, 0.f, 0.f, 0.f}, accH = accS;
    {
      const __hip_bfloat16* B = wihb + (size_t)(g * 512 + jb) * 256 + hi * 8;
#pragma unroll
      for (int kk = 0; kk < 8; ++kk) {
        bf16x8 a = *(const bf16x8*)(sL + (kk * 64 + lane) * 8);
        accS = __builtin_amdgcn_mfma_f32_16x16x32_bf16(a, *(const bf16x8*)(B + kk * 32),
                                                       accS, 0, 0, 0);
      }
    }
    if (t > 0) {
      const __hip_bfloat16* A = hb_in + (row0 + l15) * 512 + hi * 8;
      const __hip_bfloat16* B = whhb + (size_t)(g * 512 + jb) * 512 + hi * 8;
#pragma unroll
      for (int kk = 0; kk < 16; ++kk) {
        bf16x8 a = *(const bf16x8*)(A + kk * 32);
        accH = __builtin_amdgcn_mfma_f32_16x16x32_bf16(a, *(const bf16x8*)(B + kk * 32),
                                                       accH, 0, 0, 0);
      }
    }
    if (g < 2) {
#pragma unroll
      for (int i = 0; i < 4; ++i)
        accL[g][ct2][(hi * 4 + i) * 16 + l15] = accS[i] + accH[i];
    } else {
#pragma unroll
      for (int i = 0; i < 4; ++i) {
        accL[2][ct2][(hi * 4 + i) * 16 + l15] = accS[i];
        accL[3][ct2][(hi * 4 + i) * 16 + l15] = accH[i];
      }
    }
  }
  __syncthreads();

  // ---- epilogue: waves 0..1 (wave = 16-col tile); writes hb_out + hS (K=32 frag order) ----
  if (w < 2) {
    f32x4 vR = *(const f32x4*)&accL[0][w][lane * 4];
    f32x4 vZ = *(const f32x4*)&accL[1][w][lane * 4];
    f32x4 vXN = *(const f32x4*)&accL[2][w][lane * 4];
    f32x4 vHN = *(const f32x4*)&accL[3][w][lane * 4];
    const int r = lane >> 2;
    const int row = row0 + r;
    const float u0 = actions[row * 32 + t * 2 + 0];
    const float u1 = actions[row * 32 + t * 2 + 1];
#pragma unroll
    for (int j = 0; j < 4; ++j) {
      const int c = (lane & 3) * 4 + j;
      const int kloc = w * 16 + c;               // 0..31 local
      const int col = cg * 32 + kloc;
      const float4 b0 = *(const float4*)(bcol + col * 12);
      const float4 b1 = *(const float4*)(bcol + col * 12 + 4);
      const float4 b2 = *(const float4*)(bcol + col * 12 + 8);
      const float gr = vR[j] + b0.x + u0 * b1.x + u1 * b1.y;
      const float gz = vZ[j] + b0.y + u0 * b1.z + u1 * b1.w;
      const float gxn = vXN[j] + b0.z + u0 * b2.x + u1 * b2.y;
      const float ghn = vHN[j] + b0.w;
      const float rg = 1.0f / (1.0f + __expf(-gr));
      const float zg = 1.0f / (1.0f + __expf(-gz));
      float xn = gxn + rg * ghn;
      xn = fminf(fmaxf(xn, -15.0f), 15.0f);
      const float e = __expf(2.0f * xn);
      const float ng = (e - 1.0f) / (e + 1.0f);
      const float hp = (t > 0) ? (float)hb_in[row * 512 + col] : 0.0f;
      const float hnv = (1.0f - zg) * ng + zg * hp;
      const __hip_bfloat16 hb = __float2bfloat16(hnv);
      hb_out[row * 512 + col] = hb;
      hS[(r + 16 * (kloc >> 3)) * 8 + (kloc & 7)] = hb;
    }
  }
  __syncthreads();

  // ---- pred partial for s(t+1): exact K=32 slice; 16 coltiles over 6 waves ----
  if (t < TM1 - 1) {
    const bf16x8 afrag = *(const bf16x8*)(hS + lane * 8);
    for (int ct = w; ct < 16; ct += 6) {
      const int pc = ct * 16 + l15;
      const __hip_bfloat16* bp = pwb + (size_t)pc * 512 + cg * 32 + hi * 8;
      f32x4 acc = {0.f, 0.f, 0.f, 0.f};
      acc = __builtin_amdgcn_mfma_f32_16x16x32_bf16(afrag, *(const bf16x8*)bp, acc, 0, 0, 0);
#pragma unroll
      for (int i = 0; i < 4; ++i)
        rp_out[((size_t)(cg * 512 + row0 + hi * 4 + i)) * 256 + pc] =
            __float2bfloat16(acc[i]);
    }
  }
}

// ---------------- final pred (slot 16), split-K-4 ----------------
__global__ __launch_bounds__(256) void pred_v2(
    const __hip_bfloat16* __restrict__ hb,
    const __hip_bfloat16* __restrict__ pwb,
    const float* __restrict__ pb,
    float* __restrict__ out,
    __hip_bfloat16* __restrict__ spb,
    int slot) {
  __shared__ float accL[4][256];
  const int tid = threadIdx.x;
  const int w = tid >> 6, lane = tid & 63;
  const int l15 = lane & 15, hi = lane >> 4;
  const int pcg = blockIdx.x, band = blockIdx.y;
  const int row0 = band * 16, pc0 = pcg * 16;
  f32x4 acc = {0.f, 0.f, 0.f, 0.f};
  const __hip_bfloat16* A = hb + (row0 + l15) * 512 + w * 128 + hi * 8;
  const __hip_bfloat16* B = pwb + (pc0 + l15) * 512 + w * 128 + hi * 8;
#pragma unroll
  for (int kk = 0; kk < 4; ++kk)
    acc = __builtin_amdgcn_mfma_f32_16x16x32_bf16(*(const bf16x8*)(A + kk * 32),
                                                  *(const bf16x8*)(B + kk * 32),
                                                  acc, 0, 0, 0);
#pragma unroll
  for (int i = 0; i < 4; ++i) accL[w][(hi * 4 + i) * 16 + l15] = acc[i];
  __syncthreads();
  if (w == 0) {
    f32x4 p0 = *(const f32x4*)&accL[0][lane * 4];
    f32x4 p1 = *(const f32x4*)&accL[1][lane * 4];
    f32x4 p2 = *(const f32x4*)&accL[2][lane * 4];
    f32x4 p3 = *(const f32x4*)&accL[3][lane * 4];
    const int r = lane >> 2;
    const int row = row0 + r;
    float4 ov;
    float* po = &ov.x;
#pragma unroll
    for (int j = 0; j < 4; ++j) {
      const int c = (lane & 3) * 4 + j;
      const int col = pc0 + c;
      float v = p0[j] + p1[j] + p2[j] + p3[j] + pb[col];
      v = fmaxf(v, 0.0f);
      po[j] = v;
      spb[row * 256 + col] = __float2bfloat16(v);
    }
    *(float4*)(out + ((size_t)row * TT + slot) * 256 + pc0 + (lane & 3) * 4) = ov;
  }
}

extern "C" void kernel_launch(void* const* d_in, const int* in_sizes, int n_in,
                              void* d_out, int out_size, void* d_ws, size_t ws_size,
                              hipStream_t stream) {
  const float* x       = (const float*)d_in[0];
  const float* actions = (const float*)d_in[1];
  const float* cw      = (const float*)d_in[2];
  const float* gamma   = (const float*)d_in[3];
  const float* beta    = (const float*)d_in[4];
  const float* fcw     = (const float*)d_in[5];
  const float* fcb     = (const float*)d_in[6];
  const float* wih     = (const float*)d_in[7];
  const float* whh     = (const float*)d_in[8];
  const float* bih     = (const float*)d_in[9];
  const float* bhh     = (const float*)d_in[10];
  const float* pw      = (const float*)d_in[11];
  const float* pb      = (const float*)d_in[12];
  float* out = (float*)d_out;
  float* ws  = (float*)d_ws;

  float* bstats  = ws + OFF_BSTATS;
  float* stats   = ws + OFF_STATS;
  float* pooledG = ws + OFF_POOLED;
  float* bcol    = ws + OFF_BCOL;
  __hip_bfloat16* spb  = (__hip_bfloat16*)(ws + OFF_SPB);
  __hip_bfloat16* pwb  = (__hip_bfloat16*)(ws + OFF_PWB);
  __hip_bfloat16* wihb = (__hip_bfloat16*)(ws + OFF_WIHB);
  __hip_bfloat16* whhb = (__hip_bfloat16*)(ws + OFF_WHHB);
  __hip_bfloat16* hb0  = (__hip_bfloat16*)(ws + OFF_HB);
  __hip_bfloat16* hb1  = hb0 + 512 * 512;
  __hip_bfloat16* rp0  = (__hip_bfloat16*)(ws + OFF_RP);
  __hip_bfloat16* rp1  = rp0 + 16 * 512 * 256;

  enc_stats_prep<<<dim3(2048), dim3(256), 0, stream>>>(x, cw, bstats, wih, whh, pw,
                                                       bih, bhh, wihb, whhb, pwb, bcol);
  reduce_stats_k<<<dim3(32), dim3(256), 0, stream>>>(bstats, stats);
  enc_pool<<<dim3(2048), dim3(256), 0, stream>>>(x, cw, stats, gamma, beta, pooledG);
  for (int t = 0; t < TM1; ++t) {
    __hip_bfloat16* hbi = (t & 1) ? hb1 : hb0;
    __hip_bfloat16* hbo = (t & 1) ? hb0 : hb1;
    __hip_bfloat16* rpi = (t & 1) ? rp1 : rp0;
    __hip_bfloat16* rpo = (t & 1) ? rp0 : rp1;
    gru_v5<<<dim3(512), dim3(384), 0, stream>>>(
        hbi, hbo, rpi, rpo, wihb, whhb, pwb, pb, bcol, actions,
        pooledG, fcw, fcb, out, t);
  }
  pred_v2<<<dim3(16, 32), dim3(256), 0, stream>>>(hb0, pwb, pb, out, spb, 16);
}

// Round 19
// 295.049 us; speedup vs baseline: 1.4044x; 1.4044x over previous
//
#include <hip/hip_runtime.h>
#include <hip/hip_bf16.h>
#include <math.h>

#define TM1 16
#define TT 17

typedef __attribute__((ext_vector_type(8))) __bf16 bf16x8;
typedef __attribute__((ext_vector_type(4))) float f32x4;

// ---------------- workspace layout (float units) ----------------
#define OFF_BSTATS 0          // 32*2048 (TRANSPOSED: [stat][block])
#define OFF_STATS  65536      // 32
#define OFF_POOLED 65568      // 2048*16
#define OFF_BCOL   98336      // 512*12
#define OFF_SPB    104480     // 512*256 bf16 (final pred scratch)
#define OFF_PWB    170016     // 256*512 bf16
#define OFF_WIHB   235552     // 1536*256 bf16
#define OFF_WHHB   432160     // 1536*512 bf16
#define OFF_HB     825376     // 2 x 512*512 bf16
#define OFF_RP     1087520    // 2 x 8*512*256 fp32
// total ~12.7 MB

#define IMG_STRIDE 67
#define SLAB_ROWS 18
#define IMG_CI (SLAB_ROWS * IMG_STRIDE)

__device__ __forceinline__ void stage_slab_bf16(__hip_bfloat16* __restrict__ imgp,
                                                const float* __restrict__ xb, int slab,
                                                int tid) {
  for (int i = tid; i < 2 * SLAB_ROWS * 66; i += 256) {
    const int ci = i / (SLAB_ROWS * 66);
    const int rem = i - ci * (SLAB_ROWS * 66);
    const int lr = rem / 66, c = rem - lr * 66;
    const int gr = slab * 16 - 1 + lr;
    float v = 0.0f;
    if (gr >= 0 && gr < 64 && c >= 1 && c <= 64) v = xb[ci * 4096 + gr * 64 + (c - 1)];
    imgp[ci * IMG_CI + lr * IMG_STRIDE + c] = __float2bfloat16(v);
  }
}

__device__ __forceinline__ void make_k_offsets(int hi, int* off, int* val) {
#pragma unroll
  for (int j = 0; j < 8; ++j) {
    const int k = hi * 8 + j;
    if (k < 18) {
      const int ci = k / 9, r9 = k - ci * 9;
      const int dy = r9 / 3, dx = r9 - dy * 3;
      off[j] = ci * IMG_CI + dy * IMG_STRIDE + dx;
      val[j] = 1;
    } else {
      off[j] = 0;
      val[j] = 0;
    }
  }
}

__device__ __forceinline__ bf16x8 make_conv_bfrag(const float* __restrict__ cw,
                                                  int l15, int hi) {
  __hip_bfloat16 btmp[8];
#pragma unroll
  for (int j = 0; j < 8; ++j) {
    const int k = hi * 8 + j;
    btmp[j] = __float2bfloat16((k < 18) ? cw[l15 * 18 + k] : 0.0f);
  }
  return *(bf16x8*)btmp;
}

__device__ __forceinline__ bf16x8 make_conv_afrag(const __hip_bfloat16* __restrict__ imgp,
                                                  int yloc, int x0, int l15,
                                                  const int* off, const int* val) {
  const int base = yloc * IMG_STRIDE + x0 + l15;
  const __hip_bfloat16 z = __float2bfloat16(0.0f);
  __hip_bfloat16 atmp[8];
#pragma unroll
  for (int j = 0; j < 8; ++j) atmp[j] = val[j] ? imgp[base + off[j]] : z;
  return *(bf16x8*)atmp;
}

// ---------------- Encoder pass A ----------------
__global__ __launch_bounds__(256) void enc_stats_prep(
    const float* __restrict__ x, const float* __restrict__ cw,
    float* __restrict__ bstats,
    const float* __restrict__ wih, const float* __restrict__ whh,
    const float* __restrict__ pw,
    const float* __restrict__ bih, const float* __restrict__ bhh,
    __hip_bfloat16* __restrict__ wihb, __hip_bfloat16* __restrict__ whhb,
    __hip_bfloat16* __restrict__ pwb, float* __restrict__ bcol) {
  {
    const int n1 = 1536 * 256, n2 = 1536 * 512, n3 = 256 * 512, n4 = 512 * 12;
    int i = blockIdx.x * 256 + threadIdx.x;
    int st = gridDim.x * 256;
    for (int j = i; j < n1 + n2 + n3 + n4; j += st) {
      if (j < n1) {
        int r = j >> 8, c = j & 255;
        wihb[j] = __float2bfloat16(wih[r * 258 + c]);
      } else if (j < n1 + n2) {
        int k = j - n1;
        whhb[k] = __float2bfloat16(whh[k]);
      } else if (j < n1 + n2 + n3) {
        int k = j - n1 - n2;
        pwb[k] = __float2bfloat16(pw[k]);
      } else {
        int k = j - n1 - n2 - n3;
        int col = k / 12, e = k - col * 12;
        float v = 0.0f;
        switch (e) {
          case 0: v = bih[col] + bhh[col]; break;
          case 1: v = bih[512 + col] + bhh[512 + col]; break;
          case 2: v = bih[1024 + col]; break;
          case 3: v = bhh[1024 + col]; break;
          case 4: v = wih[col * 258 + 256]; break;
          case 5: v = wih[col * 258 + 257]; break;
          case 6: v = wih[(512 + col) * 258 + 256]; break;
          case 7: v = wih[(512 + col) * 258 + 257]; break;
          case 8: v = wih[(1024 + col) * 258 + 256]; break;
          case 9: v = wih[(1024 + col) * 258 + 257]; break;
          default: v = 0.0f; break;
        }
        bcol[k] = v;
      }
    }
  }

  __shared__ __hip_bfloat16 imgp[2 * IMG_CI];
  __shared__ float redS[4][16], redQ[4][16];
  const int tid = threadIdx.x;
  const int b = blockIdx.x >> 2, slab = blockIdx.x & 3;
  const int wv = tid >> 6, lane = tid & 63;
  const int l15 = lane & 15, hi = lane >> 4;
  stage_slab_bf16(imgp, x + b * 8192, slab, tid);

  int off[8], val[8];
  make_k_offsets(hi, off, val);
  const bf16x8 bfrag = make_conv_bfrag(cw, l15, hi);
  __syncthreads();

  float sacc = 0.0f, qacc = 0.0f;
  const f32x4 zero4 = {0.f, 0.f, 0.f, 0.f};
#pragma unroll
  for (int tp = 0; tp < 8; ++tp) {
    const int tpi = wv * 8 + tp;
    const int y0 = (tpi >> 2) * 2, x0 = (tpi & 3) * 16;
    bf16x8 a0 = make_conv_afrag(imgp, y0, x0, l15, off, val);
    bf16x8 a1 = make_conv_afrag(imgp, y0 + 1, x0, l15, off, val);
    f32x4 c0 = __builtin_amdgcn_mfma_f32_16x16x32_bf16(a0, bfrag, zero4, 0, 0, 0);
    f32x4 c1 = __builtin_amdgcn_mfma_f32_16x16x32_bf16(a1, bfrag, zero4, 0, 0, 0);
#pragma unroll
    for (int i = 0; i < 4; ++i) {
      sacc += c0[i] + c1[i];
      qacc = fmaf(c0[i], c0[i], qacc);
      qacc = fmaf(c1[i], c1[i], qacc);
    }
  }
  sacc += __shfl_down(sacc, 16); sacc += __shfl_down(sacc, 32);
  qacc += __shfl_down(qacc, 16); qacc += __shfl_down(qacc, 32);
  if (lane < 16) { redS[wv][l15] = sacc; redQ[wv][l15] = qacc; }
  __syncthreads();
  if (tid < 16)
    bstats[tid * 2048 + blockIdx.x] =
        redS[0][tid] + redS[1][tid] + redS[2][tid] + redS[3][tid];
  else if (tid < 32) {
    int c = tid - 16;
    bstats[tid * 2048 + blockIdx.x] =
        redQ[0][c] + redQ[1][c] + redQ[2][c] + redQ[3][c];
  }
}

__global__ __launch_bounds__(256) void reduce_stats_k(const float* __restrict__ bstats,
                                                      float* __restrict__ stats) {
  __shared__ float acc[4];
  const int c = blockIdx.x, tid = threadIdx.x;
  const float4 v4 = *(const float4*)(bstats + c * 2048 + tid * 8);
  const float4 w4 = *(const float4*)(bstats + c * 2048 + tid * 8 + 4);
  float v = v4.x + v4.y + v4.z + v4.w + w4.x + w4.y + w4.z + w4.w;
#pragma unroll
  for (int off = 32; off >= 1; off >>= 1) v += __shfl_down(v, off);
  if ((tid & 63) == 0) acc[tid >> 6] = v;
  __syncthreads();
  if (tid == 0) stats[c] = acc[0] + acc[1] + acc[2] + acc[3];
}

// ---------------- Encoder pass B ----------------
__global__ __launch_bounds__(256) void enc_pool(const float* __restrict__ x,
                                                const float* __restrict__ cw,
                                                const float* __restrict__ stats,
                                                const float* __restrict__ gamma,
                                                const float* __restrict__ beta,
                                                float* __restrict__ pooledG) {
  __shared__ __hip_bfloat16 imgp[2 * IMG_CI];
  __shared__ float red[4][16];
  __shared__ float statsL[32];
  const int tid = threadIdx.x;
  const int b = blockIdx.x >> 2, slab = blockIdx.x & 3;
  const int wv = tid >> 6, lane = tid & 63;
  const int l15 = lane & 15, hi = lane >> 4;
  stage_slab_bf16(imgp, x + b * 8192, slab, tid);
  if (tid < 32) statsL[tid] = stats[tid];

  int off[8], val[8];
  make_k_offsets(hi, off, val);
  const bf16x8 bfrag = make_conv_bfrag(cw, l15, hi);
  __syncthreads();

  const float invN = 1.0f / (512.0f * 4096.0f);
  const float m = statsL[l15] * invN;
  const float var = statsL[16 + l15] * invN - m * m;
  const float isd = rsqrtf(var + 1e-5f);
  const float scv = gamma[l15] * isd;
  const float shv = beta[l15] - m * scv;

  float psum = 0.0f;
  const f32x4 zero4 = {0.f, 0.f, 0.f, 0.f};
#pragma unroll
  for (int tp = 0; tp < 8; ++tp) {
    const int tpi = wv * 8 + tp;
    const int y0 = (tpi >> 2) * 2, x0 = (tpi & 3) * 16;
    bf16x8 a0 = make_conv_afrag(imgp, y0, x0, l15, off, val);
    bf16x8 a1 = make_conv_afrag(imgp, y0 + 1, x0, l15, off, val);
    f32x4 c0 = __builtin_amdgcn_mfma_f32_16x16x32_bf16(a0, bfrag, zero4, 0, 0, 0);
    f32x4 c1 = __builtin_amdgcn_mfma_f32_16x16x32_bf16(a1, bfrag, zero4, 0, 0, 0);
#pragma unroll
    for (int p = 0; p < 2; ++p) {
      const float v00 = fmaxf(fmaf(c0[2 * p + 0], scv, shv), 0.0f);
      const float v01 = fmaxf(fmaf(c0[2 * p + 1], scv, shv), 0.0f);
      const float v10 = fmaxf(fmaf(c1[2 * p + 0], scv, shv), 0.0f);
      const float v11 = fmaxf(fmaf(c1[2 * p + 1], scv, shv), 0.0f);
      psum += fmaxf(fmaxf(v00, v01), fmaxf(v10, v11));
    }
  }
  psum += __shfl_down(psum, 16);
  psum += __shfl_down(psum, 32);
  if (lane < 16) red[wv][l15] = psum;
  __syncthreads();
  if (tid < 16)
    pooledG[blockIdx.x * 16 + tid] = red[0][tid] + red[1][tid] + red[2][tid] + red[3][tid];
}

// ---------- Fused step v4: 512 thr (8 waves) ----------
// grid 256 (1D): cg = bid>>5, band = bid&31.
__global__ __launch_bounds__(512) void gru_v4(
    const __hip_bfloat16* __restrict__ hb_in,
    __hip_bfloat16* __restrict__ hb_out,
    const float* __restrict__ rp_in,
    float* __restrict__ rp_out,
    const __hip_bfloat16* __restrict__ wihb,
    const __hip_bfloat16* __restrict__ whhb,
    const __hip_bfloat16* __restrict__ pwb,
    const float* __restrict__ pb,
    const float* __restrict__ bcol,
    const float* __restrict__ actions,
    const float* __restrict__ pooledG, const float* __restrict__ fcw,
    const float* __restrict__ fcb,
    float* __restrict__ out,
    int t) {
  __shared__ __hip_bfloat16 hF[16 * 64 * 8];   // 16KB h(t) A-frags (frag order)
  __shared__ __hip_bfloat16 sL[8 * 64 * 8];    // 8KB  s(t) A-frags (frag order)
  __shared__ __hip_bfloat16 hS[2 * 64 * 8];    // 2KB  h(t+1) tile A-frags
  __shared__ float accL[4][4][256];            // 16KB
  const int tid = threadIdx.x;
  const int w = tid >> 6, lane = tid & 63;
  const int l15 = lane & 15, hi = lane >> 4;
  const int cg = blockIdx.x >> 5, band = blockIdx.x & 31;
  const int row0 = band * 16;

  if (t > 0) {
    for (int i = tid; i < 1024; i += 512) {
      int kk = i >> 6, ln = i & 63;
      *(bf16x8*)(hF + i * 8) =
          *(const bf16x8*)(hb_in + (row0 + (ln & 15)) * 512 + kk * 32 + (ln >> 4) * 8);
    }
    for (int i = tid; i < 1024; i += 512) {
      const int row = i >> 6, c4 = (i & 63) * 4;
      float4 a = *(const float4*)(pb + c4);
#pragma unroll
      for (int s = 0; s < 8; ++s) {
        const float4 p = *(const float4*)(rp_in + ((size_t)(s * 512 + row0 + row)) * 256 + c4);
        a.x += p.x; a.y += p.y; a.z += p.z; a.w += p.w;
      }
      a.x = fmaxf(a.x, 0.f); a.y = fmaxf(a.y, 0.f);
      a.z = fmaxf(a.z, 0.f); a.w = fmaxf(a.w, 0.f);
      const float av[4] = {a.x, a.y, a.z, a.w};
#pragma unroll
      for (int j = 0; j < 4; ++j) {
        const int c = c4 + j;
        sL[((c >> 5) * 64 + row + 16 * ((c & 31) >> 3)) * 8 + (c & 7)] =
            __float2bfloat16(av[j]);
      }
      if (cg == 0) *(float4*)(out + ((size_t)(row0 + row) * TT + t) * 256 + c4) = a;
    }
  } else {
    float* avgF = &accL[0][0][0];
    if (tid < 256) {
      const int r = tid >> 4, k = tid & 15;
      const int img = row0 + r;
      const float v = pooledG[(img * 4 + 0) * 16 + k] + pooledG[(img * 4 + 1) * 16 + k] +
                      pooledG[(img * 4 + 2) * 16 + k] + pooledG[(img * 4 + 3) * 16 + k];
      avgF[r * 16 + k] = v * (1.0f / 1024.0f);
    }
    __syncthreads();
    for (int i = tid; i < 4096; i += 512) {
      const int r = i >> 8, col = i & 255;
      float v = fcb[col];
#pragma unroll
      for (int k = 0; k < 16; ++k) v = fmaf(avgF[r * 16 + k], fcw[col * 16 + k], v);
      sL[((col >> 5) * 64 + r + 16 * ((col & 31) >> 3)) * 8 + (col & 7)] =
          __float2bfloat16(v);
      if (cg == 0) out[((size_t)(row0 + r) * TT + 0) * 256 + col] = v;
    }
  }
  __syncthreads();

  // ---- gates: 12 jobs over 8 waves (waves 0-3: jobs w and w+8; waves 4-7: job w) ----
#pragma unroll
  for (int rep = 0; rep < 2; ++rep) {
    int job;
    if (rep == 0) job = w;
    else { if (w >= 4) break; job = w + 8; }
    const int g = job >> 2, ct4 = job & 3;
    const int jb = cg * 64 + ct4 * 16 + l15;
    f32x4 accS = {0.f, 0.f, 0.f, 0.f}, accH = accS;
    {
      const __hip_bfloat16* B = wihb + (size_t)(g * 512 + jb) * 256 + hi * 8;
#pragma unroll
      for (int kk = 0; kk < 8; ++kk) {
        bf16x8 a = *(const bf16x8*)(sL + (kk * 64 + lane) * 8);
        accS = __builtin_amdgcn_mfma_f32_16x16x32_bf16(a, *(const bf16x8*)(B + kk * 32),
                                                       accS, 0, 0, 0);
      }
    }
    if (t > 0) {
      const __hip_bfloat16* B = whhb + (size_t)(g * 512 + jb) * 512 + hi * 8;
#pragma unroll
      for (int kk = 0; kk < 16; ++kk) {
        bf16x8 a = *(const bf16x8*)(hF + (kk * 64 + lane) * 8);
        accH = __builtin_amdgcn_mfma_f32_16x16x32_bf16(a, *(const bf16x8*)(B + kk * 32),
                                                       accH, 0, 0, 0);
      }
    }
    if (g < 2) {
#pragma unroll
      for (int i = 0; i < 4; ++i)
        accL[g][ct4][(hi * 4 + i) * 16 + l15] = accS[i] + accH[i];
    } else {
#pragma unroll
      for (int i = 0; i < 4; ++i) {
        accL[2][ct4][(hi * 4 + i) * 16 + l15] = accS[i];
        accL[3][ct4][(hi * 4 + i) * 16 + l15] = accH[i];
      }
    }
  }
  __syncthreads();

  // ---- epilogue: waves 0..3 (wave = coltile); writes hb_out and hS (frag order) ----
  if (w < 4) {
    f32x4 vR = *(const f32x4*)&accL[0][w][lane * 4];
    f32x4 vZ = *(const f32x4*)&accL[1][w][lane * 4];
    f32x4 vXN = *(const f32x4*)&accL[2][w][lane * 4];
    f32x4 vHN = *(const f32x4*)&accL[3][w][lane * 4];
    const int r = lane >> 2;
    const int row = row0 + r;
    const float u0 = actions[row * 32 + t * 2 + 0];
    const float u1 = actions[row * 32 + t * 2 + 1];
#pragma unroll
    for (int j = 0; j < 4; ++j) {
      const int c = (lane & 3) * 4 + j;
      const int kloc = w * 16 + c;
      const int col = cg * 64 + kloc;
      const float4 b0 = *(const float4*)(bcol + col * 12);
      const float4 b1 = *(const float4*)(bcol + col * 12 + 4);
      const float4 b2 = *(const float4*)(bcol + col * 12 + 8);
      const float gr = vR[j] + b0.x + u0 * b1.x + u1 * b1.y;
      const float gz = vZ[j] + b0.y + u0 * b1.z + u1 * b1.w;
      const float gxn = vXN[j] + b0.z + u0 * b2.x + u1 * b2.y;
      const float ghn = vHN[j] + b0.w;
      const float rg = 1.0f / (1.0f + __expf(-gr));
      const float zg = 1.0f / (1.0f + __expf(-gz));
      float xn = gxn + rg * ghn;
      xn = fminf(fmaxf(xn, -15.0f), 15.0f);
      const float e = __expf(2.0f * xn);
      const float ng = (e - 1.0f) / (e + 1.0f);
      const float hp = (t > 0) ? (float)hb_in[row * 512 + col] : 0.0f;
      const float hnv = (1.0f - zg) * ng + zg * hp;
      const __hip_bfloat16 hb = __float2bfloat16(hnv);
      hb_out[row * 512 + col] = hb;
      hS[((kloc >> 5) * 64 + r + 16 * ((kloc & 31) >> 3)) * 8 + (kloc & 7)] = hb;
    }
  }
  __syncthreads();

  // ---- pred partial for s(t+1): exact K=64 slice; 16 coltiles over 8 waves ----
  if (t < TM1 - 1) {
#pragma unroll
    for (int rep = 0; rep < 2; ++rep) {
      const int ct = w + rep * 8;
      const int pc = ct * 16 + l15;
      const __hip_bfloat16* bp = pwb + (size_t)pc * 512 + cg * 64 + hi * 8;
      f32x4 acc = {0.f, 0.f, 0.f, 0.f};
      acc = __builtin_amdgcn_mfma_f32_16x16x32_bf16(
          *(const bf16x8*)(hS + (0 * 64 + lane) * 8), *(const bf16x8*)(bp), acc, 0, 0, 0);
      acc = __builtin_amdgcn_mfma_f32_16x16x32_bf16(
          *(const bf16x8*)(hS + (1 * 64 + lane) * 8), *(const bf16x8*)(bp + 32), acc, 0, 0, 0);
#pragma unroll
      for (int i = 0; i < 4; ++i)
        rp_out[((size_t)(cg * 512 + row0 + hi * 4 + i)) * 256 + pc] = acc[i];
    }
  }
}

// ---------------- final pred (slot 16), split-K-4 ----------------
__global__ __launch_bounds__(256) void pred_v2(
    const __hip_bfloat16* __restrict__ hb,
    const __hip_bfloat16* __restrict__ pwb,
    const float* __restrict__ pb,
    float* __restrict__ out,
    __hip_bfloat16* __restrict__ spb,
    int slot) {
  __shared__ float accL[4][256];
  const int tid = threadIdx.x;
  const int w = tid >> 6, lane = tid & 63;
  const int l15 = lane & 15, hi = lane >> 4;
  const int pcg = blockIdx.x, band = blockIdx.y;
  const int row0 = band * 16, pc0 = pcg * 16;
  f32x4 acc = {0.f, 0.f, 0.f, 0.f};
  const __hip_bfloat16* A = hb + (row0 + l15) * 512 + w * 128 + hi * 8;
  const __hip_bfloat16* B = pwb + (pc0 + l15) * 512 + w * 128 + hi * 8;
#pragma unroll
  for (int kk = 0; kk < 4; ++kk)
    acc = __builtin_amdgcn_mfma_f32_16x16x32_bf16(*(const bf16x8*)(A + kk * 32),
                                                  *(const bf16x8*)(B + kk * 32),
                                                  acc, 0, 0, 0);
#pragma unroll
  for (int i = 0; i < 4; ++i) accL[w][(hi * 4 + i) * 16 + l15] = acc[i];
  __syncthreads();
  if (w == 0) {
    f32x4 p0 = *(const f32x4*)&accL[0][lane * 4];
    f32x4 p1 = *(const f32x4*)&accL[1][lane * 4];
    f32x4 p2 = *(const f32x4*)&accL[2][lane * 4];
    f32x4 p3 = *(const f32x4*)&accL[3][lane * 4];
    const int r = lane >> 2;
    const int row = row0 + r;
    float4 ov;
    float* po = &ov.x;
#pragma unroll
    for (int j = 0; j < 4; ++j) {
      const int c = (lane & 3) * 4 + j;
      const int col = pc0 + c;
      float v = p0[j] + p1[j] + p2[j] + p3[j] + pb[col];
      v = fmaxf(v, 0.0f);
      po[j] = v;
      spb[row * 256 + col] = __float2bfloat16(v);
    }
    *(float4*)(out + ((size_t)row * TT + slot) * 256 + pc0 + (lane & 3) * 4) = ov;
  }
}

extern "C" void kernel_launch(void* const* d_in, const int* in_sizes, int n_in,
                              void* d_out, int out_size, void* d_ws, size_t ws_size,
                              hipStream_t stream) {
  const float* x       = (const float*)d_in[0];
  const float* actions = (const float*)d_in[1];
  const float* cw      = (const float*)d_in[2];
  const float* gamma   = (const float*)d_in[3];
  const float* beta    = (const float*)d_in[4];
  const float* fcw     = (const float*)d_in[5];
  const float* fcb     = (const float*)d_in[6];
  const float* wih     = (const float*)d_in[7];
  const float* whh     = (const float*)d_in[8];
  const float* bih     = (const float*)d_in[9];
  const float* bhh     = (const float*)d_in[10];
  const float* pw      = (const float*)d_in[11];
  const float* pb      = (const float*)d_in[12];
  float* out = (float*)d_out;
  float* ws  = (float*)d_ws;

  float* bstats  = ws + OFF_BSTATS;
  float* stats   = ws + OFF_STATS;
  float* pooledG = ws + OFF_POOLED;
  float* bcol    = ws + OFF_BCOL;
  __hip_bfloat16* spb  = (__hip_bfloat16*)(ws + OFF_SPB);
  __hip_bfloat16* pwb  = (__hip_bfloat16*)(ws + OFF_PWB);
  __hip_bfloat16* wihb = (__hip_bfloat16*)(ws + OFF_WIHB);
  __hip_bfloat16* whhb = (__hip_bfloat16*)(ws + OFF_WHHB);
  __hip_bfloat16* hb0  = (__hip_bfloat16*)(ws + OFF_HB);
  __hip_bfloat16* hb1  = hb0 + 512 * 512;
  float* rp0 = ws + OFF_RP;
  float* rp1 = rp0 + 8 * 512 * 256;

  enc_stats_prep<<<dim3(2048), dim3(256), 0, stream>>>(x, cw, bstats, wih, whh, pw,
                                                       bih, bhh, wihb, whhb, pwb, bcol);
  reduce_stats_k<<<dim3(32), dim3(256), 0, stream>>>(bstats, stats);
  enc_pool<<<dim3(2048), dim3(256), 0, stream>>>(x, cw, stats, gamma, beta, pooledG);
  for (int t = 0; t < TM1; ++t) {
    __hip_bfloat16* hbi = (t & 1) ? hb1 : hb0;
    __hip_bfloat16* hbo = (t & 1) ? hb0 : hb1;
    float* rpi = (t & 1) ? rp1 : rp0;
    float* rpo = (t & 1) ? rp0 : rp1;
    gru_v4<<<dim3(256), dim3(512), 0, stream>>>(
        hbi, hbo, rpi, rpo, wihb, whhb, pwb, pb, bcol, actions,
        pooledG, fcw, fcb, out, t);
  }
  pred_v2<<<dim3(16, 32), dim3(256), 0, stream>>>(hb0, pwb, pb, out, spb, 16);
}